// Round 1
// baseline (396.334 us; speedup 1.0000x reference)
//
#include <hip/hip_runtime.h>

#define ORDER 1024
#define NCOEF 1025
#define BATCH 8192
#define REGS 17  // ceil(1025/64) coefficients per lane

// One 64-lane wave per batch row. Lane l holds coefficients k in
// [17*l, 17*l+16] in registers. Sequential over the 1024 roots:
//   c[k] <- c[k] - x_i * c[k-1]
// Descending-j in-place update uses pre-update values; the lane-boundary
// value (prev lane's c[16]) comes via __shfl_up, zeroed on lane 0.
__global__ __launch_bounds__(256) void r2p_kernel(const float* __restrict__ x,
                                                  float* __restrict__ out) {
    const int wave = threadIdx.x >> 6;
    const int lane = threadIdx.x & 63;
    int row = (int)blockIdx.x * 4 + wave;
    row = __builtin_amdgcn_readfirstlane(row);  // wave-uniform -> scalar loads

    const float* __restrict__ xr = x + (size_t)row * ORDER;
    float* __restrict__ orow = out + (size_t)row * NCOEF;

    float c[REGS];
#pragma unroll
    for (int j = 0; j < REGS; ++j) c[j] = 0.0f;
    if (lane == 0) c[0] = 1.0f;  // empty product = 1

    const bool lane0 = (lane == 0);

#pragma unroll 4
    for (int i = 0; i < ORDER; ++i) {
        const float xi = xr[i];       // uniform -> s_load, xi in SGPR
        const float nx = -xi;

        // previous lane's (old) c[16], i.e. coefficient 17*l - 1
        float t = __shfl_up(c[REGS - 1], 1);
        if (lane0) t = 0.0f;

#pragma unroll
        for (int j = REGS - 1; j >= 1; --j) {
            c[j] = fmaf(nx, c[j - 1], c[j]);
        }
        c[0] = fmaf(nx, t, c[0]);
    }

    // Write out: lane l stores k = 17*l + j for k <= 1024
#pragma unroll
    for (int j = 0; j < REGS; ++j) {
        const int k = lane * REGS + j;
        if (k < NCOEF) orow[k] = c[j];
    }
}

extern "C" void kernel_launch(void* const* d_in, const int* in_sizes, int n_in,
                              void* d_out, int out_size, void* d_ws, size_t ws_size,
                              hipStream_t stream) {
    const float* x = (const float*)d_in[0];
    float* out = (float*)d_out;
    // 4 rows (waves) per 256-thread block
    dim3 grid(BATCH / 4);
    dim3 block(256);
    hipLaunchKernelGGL(r2p_kernel, grid, block, 0, stream, x, out);
}

// Round 3
// 366.713 us; speedup vs baseline: 1.0808x; 1.0808x over previous
//
#include <hip/hip_runtime.h>

#define ORDER 1024
#define NCOEF 1025
#define BATCH 8192
#define REGS 17  // ceil(1025/64) coefficients per lane

// One 64-lane wave per batch row. Lane l holds coefficients k in
// [17*l, 17*l+16] in registers. Sequential over the 1024 roots:
//   c[k] <- c[k] - x_i * c[k-1]
// Descending-j in-place update uses pre-update values; the lane-boundary
// value (prev lane's old c[16]) comes via DPP wave_shr:1 (lane 0 gets 0
// via bound_ctrl) -- a single VALU instruction, no LDS, no lgkmcnt.

__device__ __forceinline__ float wave_shr1(float v) {
    // v_mov_b32_dpp dst, src wave_shr:1 row_mask:0xf bank_mask:0xf bound_ctrl:0
    // lane i reads lane i-1; lane 0 reads 0.
    int r = __builtin_amdgcn_update_dpp(0, __float_as_int(v),
                                        0x138 /*wave_shr:1*/, 0xf, 0xf, true);
    return __int_as_float(r);
}

__device__ __forceinline__ float sgpr_f32(float v) {
    // readfirstlane is int(int): MUST bitcast, not value-convert.
    return __int_as_float(__builtin_amdgcn_readfirstlane(__float_as_int(v)));
}

__global__ __launch_bounds__(256) void r2p_kernel(const float* __restrict__ x,
                                                  float* __restrict__ out) {
    const int wave = threadIdx.x >> 6;
    const int lane = threadIdx.x & 63;
    int row = (int)blockIdx.x * 4 + wave;
    row = __builtin_amdgcn_readfirstlane(row);  // wave-uniform -> scalar loads

    const float* __restrict__ xr = x + (size_t)row * ORDER;
    float* __restrict__ orow = out + (size_t)row * NCOEF;

    float c[REGS];
#pragma unroll
    for (int j = 0; j < REGS; ++j) c[j] = 0.0f;
    if (lane == 0) c[0] = 1.0f;  // empty product = 1

#pragma unroll 8
    for (int i = 0; i < ORDER; ++i) {
        // Root is wave-uniform; pin it to an SGPR (bitcast round-trip).
        const float xi = sgpr_f32(xr[i]);
        const float nx = -xi;

        // previous lane's (old) c[16], i.e. coefficient 17*l - 1 (0 on lane 0)
        const float t = wave_shr1(c[REGS - 1]);

#pragma unroll
        for (int j = REGS - 1; j >= 1; --j) {
            c[j] = fmaf(nx, c[j - 1], c[j]);
        }
        c[0] = fmaf(nx, t, c[0]);
    }

    // Write out: lane l stores k = 17*l + j for k <= 1024
#pragma unroll
    for (int j = 0; j < REGS; ++j) {
        const int k = lane * REGS + j;
        if (k < NCOEF) orow[k] = c[j];
    }
}

extern "C" void kernel_launch(void* const* d_in, const int* in_sizes, int n_in,
                              void* d_out, int out_size, void* d_ws, size_t ws_size,
                              hipStream_t stream) {
    const float* x = (const float*)d_in[0];
    float* out = (float*)d_out;
    dim3 grid(BATCH / 4);  // 4 rows (waves) per 256-thread block
    dim3 block(256);
    hipLaunchKernelGGL(r2p_kernel, grid, block, 0, stream, x, out);
}

// Round 4
// 227.963 us; speedup vs baseline: 1.7386x; 1.6087x over previous
//
#include <hip/hip_runtime.h>

#define ORDER 1024
#define NCOEF 1025
#define BATCH 8192

typedef float v2 __attribute__((ext_vector_type(2)));

// lane i reads lane i-1; lane 0 reads 0 (bound_ctrl). Single VALU instr.
__device__ __forceinline__ float wave_shr1(float v) {
    int r = __builtin_amdgcn_update_dpp(0, __float_as_int(v),
                                        0x138 /*wave_shr:1*/, 0xf, 0xf, true);
    return __int_as_float(r);
}

// readfirstlane is int(int): bitcast round-trip, NOT value conversion.
__device__ __forceinline__ float sgpr_f32(float v) {
    return __int_as_float(__builtin_amdgcn_readfirstlane(__float_as_int(v)));
}

// Lane-local coefficient bank, stride-9 pairing on the 17-coeff cycle:
//   p[m] = (c_m, c_{m+9})  for m=0..7   (covers j=0..7 and j=9..16)
//   x    = (dpp scratch = c_{-1}, c_8)
// Shift-by-1 source of p[m] is p[m-1] (aligned pair -> v_pk_fma_f32);
// shift-by-1 source of p[0] is x (dpp writes boundary straight into x.lo).
struct Bank { v2 p[8]; v2 x; };

// One root step: B = A + nx * shift1(A). All reads from A, writes to B
// (ping-pong) -> no in-place ordering hazards, clean packing.
__device__ __forceinline__ void step(Bank& A, Bank& B, float nx) {
    v2 nxp; nxp.x = nx; nxp.y = nx;
    A.x.x = wave_shr1(A.p[7].y);                   // c_{-1} = prev lane's c_16
    B.x.y = __builtin_fmaf(nx, A.p[7].x, A.x.y);   // c_8' = c_8 + nx*c_7
    B.p[0] = __builtin_elementwise_fma(nxp, A.x, A.p[0]);
#pragma unroll
    for (int m = 1; m < 8; ++m)
        B.p[m] = __builtin_elementwise_fma(nxp, A.p[m - 1], A.p[m]);
}

__global__ __launch_bounds__(256) void r2p_kernel(const float* __restrict__ x,
                                                  float* __restrict__ out) {
    const int wave = threadIdx.x >> 6;
    const int lane = threadIdx.x & 63;
    int row = (int)blockIdx.x * 4 + wave;
    row = __builtin_amdgcn_readfirstlane(row);

    const float* __restrict__ xr = x + (size_t)row * ORDER;
    float* __restrict__ orow = out + (size_t)row * NCOEF;

    Bank A, B;
#pragma unroll
    for (int m = 0; m < 8; ++m) {
        A.p[m].x = 0.0f; A.p[m].y = 0.0f;
        B.p[m].x = 0.0f; B.p[m].y = 0.0f;
    }
    A.x.x = 0.0f; A.x.y = 0.0f; B.x.x = 0.0f; B.x.y = 0.0f;
    if (lane == 0) A.p[0].x = 1.0f;   // c_0 = 1: empty product

    // 1024 roots = 512 ping-pong double-steps; result ends in bank A.
#pragma unroll 4
    for (int i = 0; i < ORDER; i += 2) {
        v2 xv = *(const v2*)(xr + i);  // rows are 4KB-aligned, i even -> 8B ok
        const float nx0 = -sgpr_f32(xv.x);
        const float nx1 = -sgpr_f32(xv.y);
        step(A, B, nx0);
        step(B, A, nx1);
    }

    // Store: k = 17*lane + j ; j=0..7 -> p[j].lo, j=8 -> x.hi, j=9..16 -> p[j-9].hi
#pragma unroll
    for (int j = 0; j < 8; ++j) {
        const int k = lane * 17 + j;
        if (k < NCOEF) orow[k] = A.p[j].x;
    }
    {
        const int k = lane * 17 + 8;
        if (k < NCOEF) orow[k] = A.x.y;
    }
#pragma unroll
    for (int j = 9; j < 17; ++j) {
        const int k = lane * 17 + j;
        if (k < NCOEF) orow[k] = A.p[j - 9].y;
    }
}

extern "C" void kernel_launch(void* const* d_in, const int* in_sizes, int n_in,
                              void* d_out, int out_size, void* d_ws, size_t ws_size,
                              hipStream_t stream) {
    const float* x = (const float*)d_in[0];
    float* out = (float*)d_out;
    dim3 grid(BATCH / 4);  // 4 waves (rows) per 256-thread block
    dim3 block(256);
    hipLaunchKernelGGL(r2p_kernel, grid, block, 0, stream, x, out);
}